// Round 3
// baseline (5030.472 us; speedup 1.0000x reference)
//
#include <hip/hip_runtime.h>
#include <math.h>

// ---------------- constants ----------------
#define Bz    8
#define Tt    8192
#define NEU   256
#define Dm    1024
#define Hh    16
#define Ll    8
#define FFd   4096
#define HDd   64
#define KL    14
#define BLANK 41
#define DIPd  40
#define GKS   20
#define TmD   8193              // T+1 after even-kernel conv
#define Ss    585               // Tm // KL
#define PEIN  3584              // KL*NEU
#define MTOK  (Bz * Ss)         // 4680
#define SpV   608               // Ss padded to multiple of 32 (V^T inner dim)
#define TCH   128               // smooth time-chunk per block

#define NEG_INF (-3.4e38f)

typedef __attribute__((ext_vector_type(8))) short short8;
typedef __attribute__((ext_vector_type(4))) float f32x4;
typedef unsigned short ushort_t;

__device__ __forceinline__ float bf2f(ushort_t u) {
  union { unsigned int i; float f; } v; v.i = ((unsigned int)u) << 16; return v.f;
}
__device__ __forceinline__ ushort_t f2bf(float f) {
  union { float f; unsigned int i; } v; v.f = f;
  unsigned int x = v.i;
  if ((x & 0x7fffffffu) > 0x7f800000u) return 0x7fc0;
  return (ushort_t)((x + 0x7fffu + ((x >> 16) & 1u)) >> 16);
}

// ---------------- gaussian smoothing along time ----------------
// Register sliding window: one block per (b, TCH-step chunk); thread = channel.
// Each input value loaded once (plus 19-row chunk overlap), coalesced.
__global__ __launch_bounds__(256) void smooth_kernel(
    const float* __restrict__ neural, float* __restrict__ out) {
  const int b = blockIdx.y, c = threadIdx.x;
  const int t0 = blockIdx.x * TCH;
  float w[GKS];
  float wsum = 0.f;
#pragma unroll
  for (int j = 0; j < GKS; j++) {
    float e = (j - 9.5f) * 0.5f;
    w[j] = expf(-0.5f * e * e);
    wsum += w[j];
  }
  const float inv = 1.f / wsum;
#pragma unroll
  for (int j = 0; j < GKS; j++) w[j] *= inv;

  const float* src = neural + (size_t)b * Tt * NEU + c;
  float* dst = out + ((size_t)b * TmD + t0) * NEU + c;

  // window covers tt in [t0-10, t0+9] for the first output
  float win[GKS];
#pragma unroll
  for (int j = 0; j < GKS; j++) {
    const int tt = t0 - GKS / 2 + j;
    win[j] = (tt >= 0 && tt < Tt) ? src[(size_t)tt * NEU] : 0.f;
  }
  const int nt = min(TCH, TmD - t0);
  for (int t = 0; t < nt; t++) {
    // prefetch next window tail while computing
    const int tt = t0 + t + GKS / 2;
    const float nv = (tt < Tt) ? src[(size_t)tt * NEU] : 0.f;
    float acc = 0.f;
#pragma unroll
    for (int j = 0; j < GKS; j++) acc += win[j] * w[j];
    dst[(size_t)t * NEU] = acc;
#pragma unroll
    for (int j = 0; j < GKS - 1; j++) win[j] = win[j + 1];
    win[GKS - 1] = nv;
  }
}

// ---------------- day linear + softsign + length mask (in place) ----------------
#define DROWS 16
__global__ __launch_bounds__(256) void day_kernel(
    float* __restrict__ x, const float* __restrict__ dayW,
    const float* __restrict__ dayB, const int* __restrict__ day_idx,
    const int* __restrict__ lengths) {
  const int b = blockIdx.y;
  const int t0 = blockIdx.x * DROWS;
  const int c = threadIdx.x;
  const int di = day_idx[b];
  const int len = lengths[b];
  const float* W = dayW + (size_t)di * NEU * NEU;
  __shared__ float rows[DROWS][NEU];
  float* xb = x + ((size_t)b * TmD + t0) * NEU;
  const int nr = min(DROWS, TmD - t0);
  for (int r = 0; r < nr; r++) rows[r][c] = xb[(size_t)r * NEU + c];
  __syncthreads();
  float acc[DROWS];
  const float bb = dayB[(size_t)di * NEU + c];
#pragma unroll
  for (int r = 0; r < DROWS; r++) acc[r] = bb;
  for (int d = 0; d < NEU; d++) {
    const float w = W[(size_t)d * NEU + c];
#pragma unroll
    for (int r = 0; r < DROWS; r++) acc[r] += rows[r][d] * w;
  }
  for (int r = 0; r < nr; r++) {
    const int t = t0 + r;
    float v = acc[r] / (1.f + fabsf(acc[r]));
    xb[(size_t)r * NEU + c] = (t < len) ? v : 0.f;
  }
}

// ---------------- generic layernorm (fp32 in, fp32 or bf16 out) ----------------
__global__ __launch_bounds__(256) void ln_kernel(
    const float* __restrict__ in, const float* __restrict__ w,
    const float* __restrict__ bias, float* __restrict__ dstf,
    ushort_t* __restrict__ dstb,
    int N, float eps, int inner, long strideA, long strideB) {
  const int row = blockIdx.x;
  const float* src = in + (size_t)(row / inner) * strideA + (size_t)(row % inner) * strideB;
  const int tid = threadIdx.x;
  float s = 0.f, ss = 0.f;
  for (int i = tid; i < N; i += 256) {
    float v = src[i];
    s += v; ss += v * v;
  }
  __shared__ float rs[256], rss[256];
  rs[tid] = s; rss[tid] = ss;
  __syncthreads();
  for (int k = 128; k > 0; k >>= 1) {
    if (tid < k) { rs[tid] += rs[tid + k]; rss[tid] += rss[tid + k]; }
    __syncthreads();
  }
  const float mean = rs[0] / N;
  const float var = rss[0] / N - mean * mean;
  const float rstd = rsqrtf(var + eps);
  for (int i = tid; i < N; i += 256) {
    const float r = (src[i] - mean) * rstd * w[i] + bias[i];
    if (dstf) dstf[(size_t)row * N + i] = r;
    else dstb[(size_t)row * N + i] = f2bf(r);
  }
}

// ---------------- fp32 -> bf16 transpose (+ K zero-pad) ----------------
// in: [R][C] fp32, out: [C][Rp] bf16, out[c][r] = (r<R) ? in[r][c] : 0
__global__ __launch_bounds__(256) void convt_kernel(
    const float* __restrict__ in, ushort_t* __restrict__ out,
    int R, int C, int Rp) {
  __shared__ float t[32][33];
  const int r0 = blockIdx.x * 32, c0 = blockIdx.y * 32;
  const int tx = threadIdx.x, ty = threadIdx.y;   // 32 x 8
#pragma unroll
  for (int i = 0; i < 4; i++) {
    const int r = r0 + ty + i * 8, c = c0 + tx;
    t[ty + i * 8][tx] = (r < R && c < C) ? in[(size_t)r * C + c] : 0.f;
  }
  __syncthreads();
#pragma unroll
  for (int i = 0; i < 4; i++) {
    const int c = c0 + ty + i * 8, r = r0 + tx;
    if (c < C && r < Rp) out[(size_t)c * Rp + r] = f2bf(t[tx][ty + i * 8]);
  }
}

// ---------------- fp32 -> bf16 elementwise ----------------
__global__ __launch_bounds__(256) void f2b_kernel(
    const float* __restrict__ in, ushort_t* __restrict__ out, int n) {
  for (int i = blockIdx.x * 256 + threadIdx.x; i < n; i += gridDim.x * 256)
    out[i] = f2bf(in[i]);
}

// ---------------- bf16 MFMA GEMM: C = epi(A[M,K] @ Bt[N,K]^T + bias) ----------------
// epi 0: store fp32  1: gelu->bf16  2: fp32 C += r  3: masked fp32 C += r  4: store bf16
#define BM 128
#define BN 128
#define BKh 32
__global__ __launch_bounds__(256) void gemm_bf16(
    const ushort_t* __restrict__ A, const ushort_t* __restrict__ Bt,
    const float* __restrict__ bias, float* __restrict__ Cf,
    ushort_t* __restrict__ Cb, int M, int N, int K, int epi,
    const int* __restrict__ eff) {
  __shared__ short As[BM * BKh];   // [row][32] bf16, 64 B/row
  __shared__ short Bs[BN * BKh];   // [n]  [32] bf16
  const int tid = threadIdx.x;
  const int wave = tid >> 6, lane = tid & 63;
  const int lm = lane & 15, quad = lane >> 4;
  const int bm = blockIdx.x * BM, bn = blockIdx.y * BN;
  const int wm = (wave >> 1) * 64, wn = (wave & 1) * 64;

  f32x4 acc[4][4] = {};

  const int ldrow = lane >> 2;          // 0..15
  const int ldk = (lane & 3) * 8;       // k offset in halfs

  for (int k0 = 0; k0 < K; k0 += BKh) {
#pragma unroll
    for (int r = 0; r < 4; r++) {
      const int cid = wave * 4 + r;     // 0..15, wave-uniform
      if (cid < 8) {
        int row = bm + cid * 16 + ldrow;
        row = min(row, M - 1);
        const ushort_t* gp = A + (size_t)row * K + k0 + ldk;
        __builtin_amdgcn_global_load_lds(
            (const __attribute__((address_space(1))) unsigned int*)gp,
            (__attribute__((address_space(3))) unsigned int*)((char*)As + cid * 1024),
            16, 0, 0);
      } else {
        int row = bn + (cid - 8) * 16 + ldrow;
        row = min(row, N - 1);
        const ushort_t* gp = Bt + (size_t)row * K + k0 + ldk;
        __builtin_amdgcn_global_load_lds(
            (const __attribute__((address_space(1))) unsigned int*)gp,
            (__attribute__((address_space(3))) unsigned int*)((char*)Bs + (cid - 8) * 1024),
            16, 0, 0);
      }
    }
    __syncthreads();
    short8 af[4], bf[4];
#pragma unroll
    for (int mt = 0; mt < 4; mt++)
      af[mt] = *(const short8*)&As[(wm + mt * 16 + lm) * BKh + quad * 8];
#pragma unroll
    for (int nt = 0; nt < 4; nt++)
      bf[nt] = *(const short8*)&Bs[(wn + nt * 16 + lm) * BKh + quad * 8];
#pragma unroll
    for (int mt = 0; mt < 4; mt++)
#pragma unroll
      for (int nt = 0; nt < 4; nt++)
        acc[mt][nt] = __builtin_amdgcn_mfma_f32_16x16x32_bf16(
            af[mt], bf[nt], acc[mt][nt], 0, 0, 0);
    __syncthreads();
  }

#pragma unroll
  for (int mt = 0; mt < 4; mt++) {
#pragma unroll
    for (int r = 0; r < 4; r++) {
      const int gm = bm + wm + mt * 16 + quad * 4 + r;
      if (gm >= M) continue;
      bool masked = false;
      if (epi == 3) masked = ((gm % Ss) >= eff[gm / Ss]);
#pragma unroll
      for (int nt = 0; nt < 4; nt++) {
        const int gn = bn + wn + nt * 16 + lm;
        if (gn >= N) continue;
        const float v = acc[mt][nt][r] + bias[gn];
        const size_t o = (size_t)gm * N + gn;
        if (epi == 0) Cf[o] = v;
        else if (epi == 1) Cb[o] = f2bf(0.5f * v * (1.f + erff(v * 0.70710678118654752f)));
        else if (epi == 2) Cf[o] += v;
        else if (epi == 3) { if (!masked) Cf[o] += v; }
        else Cb[o] = f2bf(v);
      }
    }
  }
}

// ---------------- V transpose: qkv V-slab -> Vt[b][h][d][SpV] bf16 ----------------
// grid: (SpV/32, Hh*2, Bz), block (32, 8). blockIdx.y = h*2 + d-half.
__global__ __launch_bounds__(256) void vt_kernel(
    const ushort_t* __restrict__ qkv, ushort_t* __restrict__ vt) {
  __shared__ ushort_t t[32][33];
  const int s0 = blockIdx.x * 32;
  const int h = blockIdx.y >> 1, d0 = (blockIdx.y & 1) * 32;
  const int b = blockIdx.z;
  const int tx = threadIdx.x, ty = threadIdx.y;
#pragma unroll
  for (int i = 0; i < 4; i++) {
    const int s = s0 + ty + i * 8;
    t[ty + i * 8][tx] = (s < Ss)
        ? qkv[((size_t)(b * Ss + s) * 3 + 2) * Dm + h * HDd + d0 + tx]
        : (ushort_t)0;
  }
  __syncthreads();
#pragma unroll
  for (int i = 0; i < 4; i++) {
    const int d = d0 + ty + i * 8;
    vt[((size_t)(b * Hh + h) * HDd + d) * SpV + s0 + tx] = t[tx][ty + i * 8];
  }
}

// ---------------- MFMA flash attention ----------------
// One wave per 16-row q-tile, 4 independent waves/block (no barriers).
// k-tiles of 32 keys. Online softmax; per-row (m,l) replicated across the
// 16-lane C-layout groups (col=lane&15, row=(lane>>4)*4+r).
// Blocks reversed so tallest (most causal work) q-tiles dispatch first.
__global__ __launch_bounds__(256) void fattn_kernel(
    const ushort_t* __restrict__ qkv, const ushort_t* __restrict__ vt,
    ushort_t* __restrict__ out, const int* __restrict__ eff) {
  const int wave = threadIdx.x >> 6, lane = threadIdx.x & 63;
  const int lm = lane & 15, quad = lane >> 4;
  const int nQT = (Ss + 15) / 16;                      // 37
  const int qt = ((int)gridDim.x - 1 - (int)blockIdx.x) * 4 + wave;
  if (qt >= nQT) return;
  const int h = blockIdx.y, b = blockIdx.z;
  const int e = eff[b];
  __shared__ ushort_t pl[4][16][40];                   // per-wave P scratch (padded)
  const int q0 = qt * 16;

  // Q A-frags: row = lm, d = quad*8 + j (two 32-wide d-halves)
  const int qrow = min(q0 + lm, Ss - 1);
  const short8* qp = (const short8*)(qkv + (size_t)(b * Ss + qrow) * 3 * Dm + h * HDd + quad * 8);
  const short8 aq0 = qp[0], aq1 = qp[4];

  f32x4 acc[4] = {};
  float mrow[4], lrow[4];
#pragma unroll
  for (int r = 0; r < 4; r++) { mrow[r] = NEG_INF; lrow[r] = 0.f; }

  const int kmax = min(q0 + 15, e - 1);
  const int ntiles = (kmax >> 5) + 1;

  for (int kt = 0; kt < ntiles; kt++) {
    const int k0 = kt * 32;
    // --- QK^T: K rows are native Bt-fragments (d contiguous) ---
    f32x4 s0 = {}, s1 = {};
    {
      const int c = min(k0 + lm, Ss - 1);
      const short8* kp = (const short8*)(qkv + ((size_t)(b * Ss + c) * 3 + 1) * Dm + h * HDd + quad * 8);
      s0 = __builtin_amdgcn_mfma_f32_16x16x32_bf16(aq0, kp[0], s0, 0, 0, 0);
      s0 = __builtin_amdgcn_mfma_f32_16x16x32_bf16(aq1, kp[4], s0, 0, 0, 0);
    }
    {
      const int c = min(k0 + 16 + lm, Ss - 1);
      const short8* kp = (const short8*)(qkv + ((size_t)(b * Ss + c) * 3 + 1) * Dm + h * HDd + quad * 8);
      s1 = __builtin_amdgcn_mfma_f32_16x16x32_bf16(aq0, kp[0], s1, 0, 0, 0);
      s1 = __builtin_amdgcn_mfma_f32_16x16x32_bf16(aq1, kp[4], s1, 0, 0, 0);
    }
    // --- scale + causal/length mask ---
    float sv0[4], sv1[4], tm[4];
#pragma unroll
    for (int r = 0; r < 4; r++) {
      const int row = q0 + quad * 4 + r;
      const int jm = min(row, e - 1);
      sv0[r] = (k0 + lm <= jm) ? s0[r] * 0.125f : NEG_INF;
      sv1[r] = (k0 + 16 + lm <= jm) ? s1[r] * 0.125f : NEG_INF;
      tm[r] = fmaxf(sv0[r], sv1[r]);
    }
    // --- row max over the 16-lane group ---
#pragma unroll
    for (int off = 8; off; off >>= 1)
#pragma unroll
      for (int r = 0; r < 4; r++) tm[r] = fmaxf(tm[r], __shfl_xor(tm[r], off));
    // --- online softmax update ---
    float ps[4];
#pragma unroll
    for (int r = 0; r < 4; r++) {
      const float nm = fmaxf(mrow[r], tm[r]);
      const float sc = expf(mrow[r] - nm);
      mrow[r] = nm;
      const float p0 = expf(sv0[r] - nm);
      const float p1 = expf(sv1[r] - nm);
      sv0[r] = p0; sv1[r] = p1;
      ps[r] = p0 + p1;
      lrow[r] *= sc;
#pragma unroll
      for (int nt = 0; nt < 4; nt++) acc[nt][r] *= sc;
    }
#pragma unroll
    for (int off = 8; off; off >>= 1)
#pragma unroll
      for (int r = 0; r < 4; r++) ps[r] += __shfl_xor(ps[r], off);
    // --- P: C-layout -> A-layout via per-wave LDS (wave-synchronous) ---
#pragma unroll
    for (int r = 0; r < 4; r++) {
      lrow[r] += ps[r];
      pl[wave][quad * 4 + r][lm] = f2bf(sv0[r]);
      pl[wave][quad * 4 + r][16 + lm] = f2bf(sv1[r]);
    }
    const short8 pf = *(const short8*)&pl[wave][lm][quad * 8];
    // --- PV: Vt rows (key contiguous) are native Bt-fragments ---
    const ushort_t* vtb = vt + (size_t)(b * Hh + h) * HDd * SpV + k0 + quad * 8;
#pragma unroll
    for (int nt = 0; nt < 4; nt++) {
      const short8 vf = *(const short8*)(vtb + (size_t)(nt * 16 + lm) * SpV);
      acc[nt] = __builtin_amdgcn_mfma_f32_16x16x32_bf16(pf, vf, acc[nt], 0, 0, 0);
    }
  }

#pragma unroll
  for (int r = 0; r < 4; r++) {
    const int row = q0 + quad * 4 + r;
    if (row >= Ss) continue;
    const float inv = 1.f / lrow[r];
#pragma unroll
    for (int nt = 0; nt < 4; nt++)
      out[(size_t)(b * Ss + row) * Dm + h * HDd + nt * 16 + lm] = f2bf(acc[nt][r] * inv);
  }
}

// ---------------- log_softmax over 41, optional bf16 probs (padded to 64) ----------------
__global__ __launch_bounds__(64) void lsm41_kernel(
    const float* __restrict__ in, float* __restrict__ lp,
    ushort_t* __restrict__ probs) {
  const int row = blockIdx.x, t = threadIdx.x;
  const float z = (t < BLANK) ? in[(size_t)row * BLANK + t] : NEG_INF;
  float m = z;
#pragma unroll
  for (int off = 32; off; off >>= 1) m = fmaxf(m, __shfl_xor(m, off));
  float s = (t < BLANK) ? expf(z - m) : 0.f;
#pragma unroll
  for (int off = 32; off; off >>= 1) s += __shfl_xor(s, off);
  const float l = z - m - logf(s);
  if (t < BLANK) lp[(size_t)row * BLANK + t] = l;
  if (probs) probs[(size_t)row * 64 + t] = (t < BLANK) ? f2bf(expf(l)) : 0;
}

// ---------------- diphone marginalization ----------------
__global__ __launch_bounds__(64) void diphone_kernel(
    const float* __restrict__ in, float* __restrict__ out) {
  __shared__ float z[DIPd * DIPd];
  __shared__ float u[DIPd];
  const int row = blockIdx.x, t = threadIdx.x;
  for (int i = t; i < DIPd * DIPd; i += 64) z[i] = in[(size_t)row * (DIPd * DIPd) + i];
  __syncthreads();
  if (t < DIPd) {
    float m1 = NEG_INF;
    for (int j = 0; j < DIPd; j++) m1 = fmaxf(m1, z[t * DIPd + j]);
    float s1 = 0.f;
    for (int j = 0; j < DIPd; j++) s1 += expf(z[t * DIPd + j] - m1);
    const float lr = m1 + logf(s1);
    float m2 = NEG_INF;
    for (int j = 0; j < DIPd; j++) m2 = fmaxf(m2, z[j * DIPd + t]);
    float s2 = 0.f;
    for (int j = 0; j < DIPd; j++) s2 += expf(z[j * DIPd + t] - m2);
    const float lc = m2 + logf(s2);
    const float mx = fmaxf(lr, lc), mn = fminf(lr, lc);
    u[t] = mx + log1pf(expf(mn - mx));
  }
  __syncthreads();
  const float v = (t < DIPd) ? u[t] : NEG_INF;
  float m = v;
#pragma unroll
  for (int off = 32; off; off >>= 1) m = fmaxf(m, __shfl_xor(m, off));
  float s = (t < DIPd) ? expf(v - m) : 0.f;
#pragma unroll
  for (int off = 32; off; off >>= 1) s += __shfl_xor(s, off);
  const float lse = m + logf(s);
  if (t < DIPd) out[(size_t)row * DIPd + t] = v - lse;
}

__global__ void eff_kernel(const int* __restrict__ lengths, int* __restrict__ eff) {
  const int t = threadIdx.x;
  if (t < Bz) {
    int e = lengths[t] / KL;
    eff[t] = e < 1 ? 1 : e;
  }
}

// ---------------- host ----------------
extern "C" void kernel_launch(void* const* d_in, const int* in_sizes, int n_in,
                              void* d_out, int out_size, void* d_ws, size_t ws_size,
                              hipStream_t stream) {
  (void)in_sizes; (void)n_in; (void)out_size; (void)ws_size;
  const float* neural     = (const float*)d_in[0];
  const int*   lengths    = (const int*)d_in[1];
  const int*   day_idx    = (const int*)d_in[2];
  const float* day_W      = (const float*)d_in[3];
  const float* day_b      = (const float*)d_in[4];
  const float* pe_ln1_w   = (const float*)d_in[5];
  const float* pe_ln1_b   = (const float*)d_in[6];
  const float* pe_W       = (const float*)d_in[7];
  const float* pe_b       = (const float*)d_in[8];
  const float* pe_ln2_w   = (const float*)d_in[9];
  const float* pe_ln2_b   = (const float*)d_in[10];
  const float* ln_attn_w  = (const float*)d_in[11];
  const float* ln_attn_b  = (const float*)d_in[12];
  const float* qkv_W      = (const float*)d_in[13];
  const float* qkv_b      = (const float*)d_in[14];
  const float* attn_out_W = (const float*)d_in[15];
  const float* attn_out_b = (const float*)d_in[16];
  const float* ff_ln_w    = (const float*)d_in[17];
  const float* ff_ln_b    = (const float*)d_in[18];
  const float* fc1_W      = (const float*)d_in[19];
  const float* fc1_b      = (const float*)d_in[20];
  const float* fc2_W      = (const float*)d_in[21];
  const float* fc2_b      = (const float*)d_in[22];
  const float* final_ln_w = (const float*)d_in[23];
  const float* final_ln_b = (const float*)d_in[24];
  const float* ih_W       = (const float*)d_in[25];
  const float* ih_b       = (const float*)d_in[26];
  const float* fb_W       = (const float*)d_in[27];
  const float* fb_b       = (const float*)d_in[28];
  const float* fh_W       = (const float*)d_in[29];
  const float* fh_b       = (const float*)d_in[30];
  const float* dh_W       = (const float*)d_in[31];
  const float* dh_b       = (const float*)d_in[32];

  float* out = (float*)d_out;
  char* p = (char*)d_ws;

  float*    buf_x    = (float*)p;          p += 67117056;   // 8*8193*256 fp32
  ushort_t* buf_pein = (ushort_t*)p;                        // pe-LN out, later qkv
  ushort_t* buf_qkv  = (ushort_t*)p;       p += 33546240;   // 4680*3584 bf16
  float*    buf_h    = (float*)p;          p += 19169280;   // 4680*1024 fp32
  ushort_t* buf_abf  = (ushort_t*)p;       p += 9584640;    // 4680*1024 bf16
  ushort_t* buf_ao   = (ushort_t*)p;       p += 9584640;
  char*     ffp      = p;                  p += 38338560;   // 4680*4096 bf16
  ushort_t* wbuf     = (ushort_t*)p;       p += 25380864;   // 12,690,432 bf16
  int*      eff      = (int*)p;            p += 32;

  ushort_t* buf_ff   = (ushort_t*)ffp;
  float*    buf_dip  = (float*)ffp;                         // overlays (dead ff)
  float*    buf_blank= (float*)(ffp + 29952000);
  ushort_t* buf_probs= (ushort_t*)(ffp + 30719520);
  float*    buf_peout= buf_x;                               // overlays buf_x (dead)
  ushort_t* buf_vt   = (ushort_t*)buf_x;                    // V^T, overlays buf_x (dead after pe)
                                                            // 8*16*64*608*2 = 9,961,472 B < 67 MB

  // wbuf element offsets
  ushort_t* qkvT = wbuf;                 // 3,145,728
  ushort_t* aoT  = wbuf + 3145728;       // 1,048,576
  ushort_t* fc1T = wbuf + 4194304;       // 4,194,304
  ushort_t* fc2T = wbuf + 8388608;       // 4,194,304
  ushort_t* ihT  = wbuf + 12582912;      // 41,984
  ushort_t* fbT  = wbuf + 12624896;      // 65,536
  ushort_t* peT  = wbuf;                 // pre-loop only (3,670,016)
  ushort_t* dhT  = wbuf;                 // post-loop (1,638,400)
  ushort_t* fhT  = wbuf + 1638400;       // post-loop (41,984)

  auto convt = [&](const float* in, ushort_t* o, int R, int C, int Rp) {
    dim3 g((Rp + 31) / 32, (C + 31) / 32);
    convt_kernel<<<g, dim3(32, 8), 0, stream>>>(in, o, R, C, Rp);
  };
  auto gemm = [&](const ushort_t* A, const ushort_t* Bt, const float* bias,
                  float* Cf, ushort_t* Cb, int M_, int N_, int K_, int epi) {
    dim3 g((M_ + BM - 1) / BM, (N_ + BN - 1) / BN);
    gemm_bf16<<<g, 256, 0, stream>>>(A, Bt, bias, Cf, Cb, M_, N_, K_, epi, eff);
  };

  eff_kernel<<<1, 64, 0, stream>>>(lengths, eff);
  smooth_kernel<<<dim3((TmD + TCH - 1) / TCH, Bz), 256, 0, stream>>>(neural, buf_x);
  day_kernel<<<dim3((TmD + DROWS - 1) / DROWS, Bz), 256, 0, stream>>>(buf_x, day_W, day_b, day_idx, lengths);

  ln_kernel<<<MTOK, 256, 0, stream>>>(buf_x, pe_ln1_w, pe_ln1_b, nullptr, buf_pein,
                                      PEIN, 1e-6f, Ss, (long)TmD * NEU, (long)KL * NEU);
  convt(pe_W, peT, PEIN, Dm, PEIN);
  convt(ih_W, ihT, Dm, BLANK, Dm);
  convt(fb_W, fbT, BLANK, Dm, 64);
  gemm(buf_pein, peT, pe_b, buf_peout, nullptr, MTOK, Dm, PEIN, 0);
  ln_kernel<<<MTOK, 256, 0, stream>>>(buf_peout, pe_ln2_w, pe_ln2_b, buf_h, nullptr,
                                      Dm, 1e-6f, MTOK, 0L, (long)Dm);

  const int nQT = (Ss + 15) / 16;        // 37
  const int fgx = (nQT + 3) / 4;         // 10

  for (int i = 0; i < Ll; i++) {
    convt(qkv_W + (size_t)i * Dm * 3 * Dm, qkvT, Dm, 3 * Dm, Dm);
    convt(attn_out_W + (size_t)i * Dm * Dm, aoT, Dm, Dm, Dm);
    convt(fc1_W + (size_t)i * Dm * FFd, fc1T, Dm, FFd, Dm);
    convt(fc2_W + (size_t)i * FFd * Dm, fc2T, FFd, Dm, FFd);

    ln_kernel<<<MTOK, 256, 0, stream>>>(buf_h, ln_attn_w + (size_t)i * Dm,
                                        ln_attn_b + (size_t)i * Dm, nullptr, buf_abf,
                                        Dm, 1e-5f, MTOK, 0L, (long)Dm);
    gemm(buf_abf, qkvT, qkv_b + (size_t)i * 3 * Dm, nullptr, buf_qkv,
         MTOK, 3 * Dm, Dm, 4);
    vt_kernel<<<dim3(SpV / 32, Hh * 2, Bz), dim3(32, 8), 0, stream>>>(buf_qkv, buf_vt);
    fattn_kernel<<<dim3(fgx, Hh, Bz), 256, 0, stream>>>(buf_qkv, buf_vt, buf_ao, eff);
    gemm(buf_ao, aoT, attn_out_b + (size_t)i * Dm, buf_h, nullptr,
         MTOK, Dm, Dm, 3);
    ln_kernel<<<MTOK, 256, 0, stream>>>(buf_h, ff_ln_w + (size_t)i * Dm,
                                        ff_ln_b + (size_t)i * Dm, nullptr, buf_abf,
                                        Dm, 1e-5f, MTOK, 0L, (long)Dm);
    gemm(buf_abf, fc1T, fc1_b + (size_t)i * FFd, nullptr, buf_ff,
         MTOK, FFd, Dm, 1);
    gemm(buf_ff, fc2T, fc2_b + (size_t)i * Dm, buf_h, nullptr,
         MTOK, Dm, FFd, 2);
    if (i == 3) {
      f2b_kernel<<<1024, 256, 0, stream>>>(buf_h, buf_abf, MTOK * Dm);
      gemm(buf_abf, ihT, ih_b, buf_blank, nullptr, MTOK, BLANK, Dm, 0);
      lsm41_kernel<<<MTOK, 64, 0, stream>>>(buf_blank, out + (size_t)MTOK * BLANK, buf_probs);
      gemm(buf_probs, fbT, fb_b, buf_h, nullptr, MTOK, Dm, 64, 2);
    }
  }

  ln_kernel<<<MTOK, 256, 0, stream>>>(buf_h, final_ln_w, final_ln_b, nullptr, buf_abf,
                                      Dm, 1e-5f, MTOK, 0L, (long)Dm);
  convt(dh_W, dhT, Dm, DIPd * DIPd, Dm);
  convt(fh_W, fhT, Dm, BLANK, Dm);
  gemm(buf_abf, fhT, fh_b, buf_blank, nullptr, MTOK, BLANK, Dm, 0);
  lsm41_kernel<<<MTOK, 64, 0, stream>>>(buf_blank, out, nullptr);
  gemm(buf_abf, dhT, dh_b, buf_dip, nullptr, MTOK, DIPd * DIPd, Dm, 0);
  diphone_kernel<<<MTOK, 64, 0, stream>>>(buf_dip, out + (size_t)2 * MTOK * BLANK);
}

// Round 4
// 4770.960 us; speedup vs baseline: 1.0544x; 1.0544x over previous
//
#include <hip/hip_runtime.h>
#include <math.h>

// ---------------- constants ----------------
#define Bz    8
#define Tt    8192
#define NEU   256
#define Dm    1024
#define Hh    16
#define Ll    8
#define FFd   4096
#define HDd   64
#define KL    14
#define BLANK 41
#define DIPd  40
#define GKS   20
#define TmD   8193              // T+1 after even-kernel conv
#define Ss    585               // Tm // KL
#define PEIN  3584              // KL*NEU
#define MTOK  (Bz * Ss)         // 4680
#define SpV   608               // Ss padded to multiple of 32 (V^T inner dim)
#define TCH   128               // smooth time-chunk per block

#define NEG_INF (-3.4e38f)

typedef __attribute__((ext_vector_type(8))) short short8;
typedef __attribute__((ext_vector_type(4))) float f32x4;
typedef __attribute__((ext_vector_type(4))) unsigned short us4;
typedef unsigned short ushort_t;

__device__ __forceinline__ float bf2f(ushort_t u) {
  union { unsigned int i; float f; } v; v.i = ((unsigned int)u) << 16; return v.f;
}
__device__ __forceinline__ ushort_t f2bf(float f) {
  union { float f; unsigned int i; } v; v.f = f;
  unsigned int x = v.i;
  if ((x & 0x7fffffffu) > 0x7f800000u) return 0x7fc0;
  return (ushort_t)((x + 0x7fffu + ((x >> 16) & 1u)) >> 16);
}

// ---------------- gaussian smoothing along time ----------------
// Register sliding window: one block per (b, TCH-step chunk); thread = channel.
__global__ __launch_bounds__(256) void smooth_kernel(
    const float* __restrict__ neural, float* __restrict__ out) {
  const int b = blockIdx.y, c = threadIdx.x;
  const int t0 = blockIdx.x * TCH;
  float w[GKS];
  float wsum = 0.f;
#pragma unroll
  for (int j = 0; j < GKS; j++) {
    float e = (j - 9.5f) * 0.5f;
    w[j] = expf(-0.5f * e * e);
    wsum += w[j];
  }
  const float inv = 1.f / wsum;
#pragma unroll
  for (int j = 0; j < GKS; j++) w[j] *= inv;

  const float* src = neural + (size_t)b * Tt * NEU + c;
  float* dst = out + ((size_t)b * TmD + t0) * NEU + c;

  float win[GKS];
#pragma unroll
  for (int j = 0; j < GKS; j++) {
    const int tt = t0 - GKS / 2 + j;
    win[j] = (tt >= 0 && tt < Tt) ? src[(size_t)tt * NEU] : 0.f;
  }
  const int nt = min(TCH, TmD - t0);
  for (int t = 0; t < nt; t++) {
    const int tt = t0 + t + GKS / 2;
    const float nv = (tt < Tt) ? src[(size_t)tt * NEU] : 0.f;
    float acc = 0.f;
#pragma unroll
    for (int j = 0; j < GKS; j++) acc += win[j] * w[j];
    dst[(size_t)t * NEU] = acc;
#pragma unroll
    for (int j = 0; j < GKS - 1; j++) win[j] = win[j + 1];
    win[GKS - 1] = nv;
  }
}

// ---------------- day W pre-transpose: out[b][c][k] = bf16(W[di[b]][k][c]) ----------------
__global__ __launch_bounds__(256) void dayt_kernel(
    const float* __restrict__ dayW, const int* __restrict__ day_idx,
    ushort_t* __restrict__ out) {
  __shared__ float t[32][33];
  const int b = blockIdx.z;
  const int k0 = blockIdx.x * 32, c0 = blockIdx.y * 32;
  const int tx = threadIdx.x, ty = threadIdx.y;   // 32 x 8
  const float* W = dayW + (size_t)day_idx[b] * NEU * NEU;
#pragma unroll
  for (int i = 0; i < 4; i++)
    t[ty + i * 8][tx] = W[(size_t)(k0 + ty + i * 8) * NEU + c0 + tx];
  __syncthreads();
  ushort_t* o = out + (size_t)b * NEU * NEU;
#pragma unroll
  for (int i = 0; i < 4; i++)
    o[(size_t)(c0 + ty + i * 8) * NEU + k0 + tx] = f2bf(t[tx][ty + i * 8]);
}

// ---------------- day linear via MFMA (split hi/lo bf16, ~fp32-exact) ----------------
// In-place x update. One block owns 64 rows x ALL 256 output channels
// (required for in-place safety: reads of the contraction dim cover all
// 256 cols of its own rows; no other block touches them).
#define DBM 64
#define DBK 32
__global__ __launch_bounds__(256) void day_mfma(
    float* __restrict__ x, const ushort_t* __restrict__ Wt,
    const float* __restrict__ dayB, const int* __restrict__ day_idx,
    const int* __restrict__ lengths) {
  const int b = blockIdx.y;
  const int bm = blockIdx.x * DBM;
  const int tid = threadIdx.x;
  const int wave = tid >> 6, lane = tid & 63;
  const int lm = lane & 15, quad = lane >> 4;
  const int di = day_idx[b];
  const int len = lengths[b];
  // rows padded to 40 halfs (80 B): 16-B aligned, ~2-way banks (free)
  __shared__ ushort_t Ahi[DBM][40], Alo[DBM][40], Bs[256][40];
  f32x4 acc[4][4] = {};
  const float* xb = x + (size_t)b * TmD * NEU;
  const ushort_t* wt = Wt + (size_t)b * NEU * NEU;

  for (int k0 = 0; k0 < NEU; k0 += DBK) {
    __syncthreads();
    // stage A (x tile 64x32 fp32 -> hi/lo bf16): 2 float4 per thread
#pragma unroll
    for (int i = 0; i < 2; i++) {
      const int f = tid + i * 256;          // 0..511
      const int row = f >> 3, kq = f & 7;
      const int gr = min(bm + row, TmD - 1);
      const float4 v = *(const float4*)&xb[(size_t)gr * NEU + k0 + kq * 4];
      const float vv[4] = {v.x, v.y, v.z, v.w};
      us4 hv, lv;
#pragma unroll
      for (int j = 0; j < 4; j++) {
        union { float f; unsigned int u; } uu; uu.f = vv[j];
        const ushort_t h = (ushort_t)(uu.u >> 16);   // truncate-to-bf16
        hv[j] = h;
        lv[j] = f2bf(vv[j] - bf2f(h));
      }
      *(us4*)&Ahi[row][kq * 4] = hv;
      *(us4*)&Alo[row][kq * 4] = lv;
    }
    // stage B (Wt tile 256c x 32k bf16): 4 short8 per thread
#pragma unroll
    for (int i = 0; i < 4; i++) {
      const int u = tid + i * 256;          // 0..1023
      const int c = u >> 2, kq8 = u & 3;
      const short8 wv = *(const short8*)&wt[(size_t)c * NEU + k0 + kq8 * 8];
      *(short8*)&Bs[c][kq8 * 8] = wv;
    }
    __syncthreads();
    short8 ah[4], al[4], bfr[4];
#pragma unroll
    for (int mt = 0; mt < 4; mt++) {
      ah[mt] = *(const short8*)&Ahi[mt * 16 + lm][quad * 8];
      al[mt] = *(const short8*)&Alo[mt * 16 + lm][quad * 8];
    }
#pragma unroll
    for (int nt = 0; nt < 4; nt++)
      bfr[nt] = *(const short8*)&Bs[wave * 64 + nt * 16 + lm][quad * 8];
#pragma unroll
    for (int mt = 0; mt < 4; mt++)
#pragma unroll
      for (int nt = 0; nt < 4; nt++) {
        acc[mt][nt] = __builtin_amdgcn_mfma_f32_16x16x32_bf16(
            ah[mt], bfr[nt], acc[mt][nt], 0, 0, 0);
        acc[mt][nt] = __builtin_amdgcn_mfma_f32_16x16x32_bf16(
            al[mt], bfr[nt], acc[mt][nt], 0, 0, 0);
      }
  }

#pragma unroll
  for (int mt = 0; mt < 4; mt++)
#pragma unroll
    for (int r = 0; r < 4; r++) {
      const int gm = bm + mt * 16 + quad * 4 + r;
      if (gm >= TmD) continue;
#pragma unroll
      for (int nt = 0; nt < 4; nt++) {
        const int gn = wave * 64 + nt * 16 + lm;
        float v = acc[mt][nt][r] + dayB[(size_t)di * NEU + gn];
        v = v / (1.f + fabsf(v));
        x[((size_t)b * TmD + gm) * NEU + gn] = (gm < len) ? v : 0.f;
      }
    }
}

// ---------------- generic layernorm (fp32 in, fp32 or bf16 out) ----------------
__global__ __launch_bounds__(256) void ln_kernel(
    const float* __restrict__ in, const float* __restrict__ w,
    const float* __restrict__ bias, float* __restrict__ dstf,
    ushort_t* __restrict__ dstb,
    int N, float eps, int inner, long strideA, long strideB) {
  const int row = blockIdx.x;
  const float* src = in + (size_t)(row / inner) * strideA + (size_t)(row % inner) * strideB;
  const int tid = threadIdx.x;
  float s = 0.f, ss = 0.f;
  for (int i = tid; i < N; i += 256) {
    float v = src[i];
    s += v; ss += v * v;
  }
  __shared__ float rs[256], rss[256];
  rs[tid] = s; rss[tid] = ss;
  __syncthreads();
  for (int k = 128; k > 0; k >>= 1) {
    if (tid < k) { rs[tid] += rs[tid + k]; rss[tid] += rss[tid + k]; }
    __syncthreads();
  }
  const float mean = rs[0] / N;
  const float var = rss[0] / N - mean * mean;
  const float rstd = rsqrtf(var + eps);
  for (int i = tid; i < N; i += 256) {
    const float r = (src[i] - mean) * rstd * w[i] + bias[i];
    if (dstf) dstf[(size_t)row * N + i] = r;
    else dstb[(size_t)row * N + i] = f2bf(r);
  }
}

// ---------------- fp32 -> bf16 transpose (+ K zero-pad) ----------------
// in: [R][C] fp32, out: [C][Rp] bf16, out[c][r] = (r<R) ? in[r][c] : 0
__global__ __launch_bounds__(256) void convt_kernel(
    const float* __restrict__ in, ushort_t* __restrict__ out,
    int R, int C, int Rp) {
  __shared__ float t[32][33];
  const int r0 = blockIdx.x * 32, c0 = blockIdx.y * 32;
  const int tx = threadIdx.x, ty = threadIdx.y;   // 32 x 8
#pragma unroll
  for (int i = 0; i < 4; i++) {
    const int r = r0 + ty + i * 8, c = c0 + tx;
    t[ty + i * 8][tx] = (r < R && c < C) ? in[(size_t)r * C + c] : 0.f;
  }
  __syncthreads();
#pragma unroll
  for (int i = 0; i < 4; i++) {
    const int c = c0 + ty + i * 8, r = r0 + tx;
    if (c < C && r < Rp) out[(size_t)c * Rp + r] = f2bf(t[tx][ty + i * 8]);
  }
}

// ---------------- fp32 -> bf16 elementwise ----------------
__global__ __launch_bounds__(256) void f2b_kernel(
    const float* __restrict__ in, ushort_t* __restrict__ out, int n) {
  for (int i = blockIdx.x * 256 + threadIdx.x; i < n; i += gridDim.x * 256)
    out[i] = f2bf(in[i]);
}

// ---------------- bf16 MFMA GEMM: C = epi(A[M,K] @ Bt[N,K]^T + bias) ----------------
// epi 0: store fp32  1: gelu->bf16  2: fp32 C += r  3: masked fp32 C += r  4: store bf16
#define BM 128
#define BN 128
#define BKh 32
__global__ __launch_bounds__(256) void gemm_bf16(
    const ushort_t* __restrict__ A, const ushort_t* __restrict__ Bt,
    const float* __restrict__ bias, float* __restrict__ Cf,
    ushort_t* __restrict__ Cb, int M, int N, int K, int epi,
    const int* __restrict__ eff) {
  __shared__ short As[BM * BKh];   // [row][32] bf16, 64 B/row
  __shared__ short Bs[BN * BKh];   // [n]  [32] bf16
  const int tid = threadIdx.x;
  const int wave = tid >> 6, lane = tid & 63;
  const int lm = lane & 15, quad = lane >> 4;
  const int bm = blockIdx.x * BM, bn = blockIdx.y * BN;
  const int wm = (wave >> 1) * 64, wn = (wave & 1) * 64;

  f32x4 acc[4][4] = {};

  const int ldrow = lane >> 2;          // 0..15
  const int ldk = (lane & 3) * 8;       // k offset in halfs

  for (int k0 = 0; k0 < K; k0 += BKh) {
#pragma unroll
    for (int r = 0; r < 4; r++) {
      const int cid = wave * 4 + r;     // 0..15, wave-uniform
      if (cid < 8) {
        int row = bm + cid * 16 + ldrow;
        row = min(row, M - 1);
        const ushort_t* gp = A + (size_t)row * K + k0 + ldk;
        __builtin_amdgcn_global_load_lds(
            (const __attribute__((address_space(1))) unsigned int*)gp,
            (__attribute__((address_space(3))) unsigned int*)((char*)As + cid * 1024),
            16, 0, 0);
      } else {
        int row = bn + (cid - 8) * 16 + ldrow;
        row = min(row, N - 1);
        const ushort_t* gp = Bt + (size_t)row * K + k0 + ldk;
        __builtin_amdgcn_global_load_lds(
            (const __attribute__((address_space(1))) unsigned int*)gp,
            (__attribute__((address_space(3))) unsigned int*)((char*)Bs + (cid - 8) * 1024),
            16, 0, 0);
      }
    }
    __syncthreads();
    short8 af[4], bf[4];
#pragma unroll
    for (int mt = 0; mt < 4; mt++)
      af[mt] = *(const short8*)&As[(wm + mt * 16 + lm) * BKh + quad * 8];
#pragma unroll
    for (int nt = 0; nt < 4; nt++)
      bf[nt] = *(const short8*)&Bs[(wn + nt * 16 + lm) * BKh + quad * 8];
#pragma unroll
    for (int mt = 0; mt < 4; mt++)
#pragma unroll
      for (int nt = 0; nt < 4; nt++)
        acc[mt][nt] = __builtin_amdgcn_mfma_f32_16x16x32_bf16(
            af[mt], bf[nt], acc[mt][nt], 0, 0, 0);
    __syncthreads();
  }

#pragma unroll
  for (int mt = 0; mt < 4; mt++) {
#pragma unroll
    for (int r = 0; r < 4; r++) {
      const int gm = bm + wm + mt * 16 + quad * 4 + r;
      if (gm >= M) continue;
      bool masked = false;
      if (epi == 3) masked = ((gm % Ss) >= eff[gm / Ss]);
#pragma unroll
      for (int nt = 0; nt < 4; nt++) {
        const int gn = bn + wn + nt * 16 + lm;
        if (gn >= N) continue;
        const float v = acc[mt][nt][r] + bias[gn];
        const size_t o = (size_t)gm * N + gn;
        if (epi == 0) Cf[o] = v;
        else if (epi == 1) Cb[o] = f2bf(0.5f * v * (1.f + erff(v * 0.70710678118654752f)));
        else if (epi == 2) Cf[o] += v;
        else if (epi == 3) { if (!masked) Cf[o] += v; }
        else Cb[o] = f2bf(v);
      }
    }
  }
}

// ---------------- V transpose: qkv V-slab -> Vt[b][h][d][SpV] bf16 ----------------
__global__ __launch_bounds__(256) void vt_kernel(
    const ushort_t* __restrict__ qkv, ushort_t* __restrict__ vt) {
  __shared__ ushort_t t[32][33];
  const int s0 = blockIdx.x * 32;
  const int h = blockIdx.y >> 1, d0 = (blockIdx.y & 1) * 32;
  const int b = blockIdx.z;
  const int tx = threadIdx.x, ty = threadIdx.y;
#pragma unroll
  for (int i = 0; i < 4; i++) {
    const int s = s0 + ty + i * 8;
    t[ty + i * 8][tx] = (s < Ss)
        ? qkv[((size_t)(b * Ss + s) * 3 + 2) * Dm + h * HDd + d0 + tx]
        : (ushort_t)0;
  }
  __syncthreads();
#pragma unroll
  for (int i = 0; i < 4; i++) {
    const int d = d0 + ty + i * 8;
    vt[((size_t)(b * Hh + h) * HDd + d) * SpV + s0 + tx] = t[tx][ty + i * 8];
  }
}

// ---------------- MFMA flash attention ----------------
__global__ __launch_bounds__(256) void fattn_kernel(
    const ushort_t* __restrict__ qkv, const ushort_t* __restrict__ vt,
    ushort_t* __restrict__ out, const int* __restrict__ eff) {
  const int wave = threadIdx.x >> 6, lane = threadIdx.x & 63;
  const int lm = lane & 15, quad = lane >> 4;
  const int nQT = (Ss + 15) / 16;                      // 37
  const int qt = ((int)gridDim.x - 1 - (int)blockIdx.x) * 4 + wave;
  if (qt >= nQT) return;
  const int h = blockIdx.y, b = blockIdx.z;
  const int e = eff[b];
  __shared__ ushort_t pl[4][16][40];                   // per-wave P scratch (padded)
  const int q0 = qt * 16;

  const int qrow = min(q0 + lm, Ss - 1);
  const short8* qp = (const short8*)(qkv + (size_t)(b * Ss + qrow) * 3 * Dm + h * HDd + quad * 8);
  const short8 aq0 = qp[0], aq1 = qp[4];

  f32x4 acc[4] = {};
  float mrow[4], lrow[4];
#pragma unroll
  for (int r = 0; r < 4; r++) { mrow[r] = NEG_INF; lrow[r] = 0.f; }

  const int kmax = min(q0 + 15, e - 1);
  const int ntiles = (kmax >> 5) + 1;

  for (int kt = 0; kt < ntiles; kt++) {
    const int k0 = kt * 32;
    f32x4 s0 = {}, s1 = {};
    {
      const int c = min(k0 + lm, Ss - 1);
      const short8* kp = (const short8*)(qkv + ((size_t)(b * Ss + c) * 3 + 1) * Dm + h * HDd + quad * 8);
      s0 = __builtin_amdgcn_mfma_f32_16x16x32_bf16(aq0, kp[0], s0, 0, 0, 0);
      s0 = __builtin_amdgcn_mfma_f32_16x16x32_bf16(aq1, kp[4], s0, 0, 0, 0);
    }
    {
      const int c = min(k0 + 16 + lm, Ss - 1);
      const short8* kp = (const short8*)(qkv + ((size_t)(b * Ss + c) * 3 + 1) * Dm + h * HDd + quad * 8);
      s1 = __builtin_amdgcn_mfma_f32_16x16x32_bf16(aq0, kp[0], s1, 0, 0, 0);
      s1 = __builtin_amdgcn_mfma_f32_16x16x32_bf16(aq1, kp[4], s1, 0, 0, 0);
    }
    float sv0[4], sv1[4], tm[4];
#pragma unroll
    for (int r = 0; r < 4; r++) {
      const int row = q0 + quad * 4 + r;
      const int jm = min(row, e - 1);
      sv0[r] = (k0 + lm <= jm) ? s0[r] * 0.125f : NEG_INF;
      sv1[r] = (k0 + 16 + lm <= jm) ? s1[r] * 0.125f : NEG_INF;
      tm[r] = fmaxf(sv0[r], sv1[r]);
    }
#pragma unroll
    for (int off = 8; off; off >>= 1)
#pragma unroll
      for (int r = 0; r < 4; r++) tm[r] = fmaxf(tm[r], __shfl_xor(tm[r], off));
    float ps[4];
#pragma unroll
    for (int r = 0; r < 4; r++) {
      const float nm = fmaxf(mrow[r], tm[r]);
      const float sc = expf(mrow[r] - nm);
      mrow[r] = nm;
      const float p0 = expf(sv0[r] - nm);
      const float p1 = expf(sv1[r] - nm);
      sv0[r] = p0; sv1[r] = p1;
      ps[r] = p0 + p1;
      lrow[r] *= sc;
#pragma unroll
      for (int nt = 0; nt < 4; nt++) acc[nt][r] *= sc;
    }
#pragma unroll
    for (int off = 8; off; off >>= 1)
#pragma unroll
      for (int r = 0; r < 4; r++) ps[r] += __shfl_xor(ps[r], off);
#pragma unroll
    for (int r = 0; r < 4; r++) {
      lrow[r] += ps[r];
      pl[wave][quad * 4 + r][lm] = f2bf(sv0[r]);
      pl[wave][quad * 4 + r][16 + lm] = f2bf(sv1[r]);
    }
    const short8 pf = *(const short8*)&pl[wave][lm][quad * 8];
    const ushort_t* vtb = vt + (size_t)(b * Hh + h) * HDd * SpV + k0 + quad * 8;
#pragma unroll
    for (int nt = 0; nt < 4; nt++) {
      const short8 vf = *(const short8*)(vtb + (size_t)(nt * 16 + lm) * SpV);
      acc[nt] = __builtin_amdgcn_mfma_f32_16x16x32_bf16(pf, vf, acc[nt], 0, 0, 0);
    }
  }

#pragma unroll
  for (int r = 0; r < 4; r++) {
    const int row = q0 + quad * 4 + r;
    if (row >= Ss) continue;
    const float inv = 1.f / lrow[r];
#pragma unroll
    for (int nt = 0; nt < 4; nt++)
      out[(size_t)(b * Ss + row) * Dm + h * HDd + nt * 16 + lm] = f2bf(acc[nt][r] * inv);
  }
}

// ---------------- log_softmax over 41, optional bf16 probs (padded to 64) ----------------
__global__ __launch_bounds__(64) void lsm41_kernel(
    const float* __restrict__ in, float* __restrict__ lp,
    ushort_t* __restrict__ probs) {
  const int row = blockIdx.x, t = threadIdx.x;
  const float z = (t < BLANK) ? in[(size_t)row * BLANK + t] : NEG_INF;
  float m = z;
#pragma unroll
  for (int off = 32; off; off >>= 1) m = fmaxf(m, __shfl_xor(m, off));
  float s = (t < BLANK) ? expf(z - m) : 0.f;
#pragma unroll
  for (int off = 32; off; off >>= 1) s += __shfl_xor(s, off);
  const float l = z - m - logf(s);
  if (t < BLANK) lp[(size_t)row * BLANK + t] = l;
  if (probs) probs[(size_t)row * 64 + t] = (t < BLANK) ? f2bf(expf(l)) : 0;
}

// ---------------- diphone marginalization ----------------
__global__ __launch_bounds__(64) void diphone_kernel(
    const float* __restrict__ in, float* __restrict__ out) {
  __shared__ float z[DIPd * DIPd];
  __shared__ float u[DIPd];
  const int row = blockIdx.x, t = threadIdx.x;
  for (int i = t; i < DIPd * DIPd; i += 64) z[i] = in[(size_t)row * (DIPd * DIPd) + i];
  __syncthreads();
  if (t < DIPd) {
    float m1 = NEG_INF;
    for (int j = 0; j < DIPd; j++) m1 = fmaxf(m1, z[t * DIPd + j]);
    float s1 = 0.f;
    for (int j = 0; j < DIPd; j++) s1 += expf(z[t * DIPd + j] - m1);
    const float lr = m1 + logf(s1);
    float m2 = NEG_INF;
    for (int j = 0; j < DIPd; j++) m2 = fmaxf(m2, z[j * DIPd + t]);
    float s2 = 0.f;
    for (int j = 0; j < DIPd; j++) s2 += expf(z[j * DIPd + t] - m2);
    const float lc = m2 + logf(s2);
    const float mx = fmaxf(lr, lc), mn = fminf(lr, lc);
    u[t] = mx + log1pf(expf(mn - mx));
  }
  __syncthreads();
  const float v = (t < DIPd) ? u[t] : NEG_INF;
  float m = v;
#pragma unroll
  for (int off = 32; off; off >>= 1) m = fmaxf(m, __shfl_xor(m, off));
  float s = (t < DIPd) ? expf(v - m) : 0.f;
#pragma unroll
  for (int off = 32; off; off >>= 1) s += __shfl_xor(s, off);
  const float lse = m + logf(s);
  if (t < DIPd) out[(size_t)row * DIPd + t] = v - lse;
}

__global__ void eff_kernel(const int* __restrict__ lengths, int* __restrict__ eff) {
  const int t = threadIdx.x;
  if (t < Bz) {
    int e = lengths[t] / KL;
    eff[t] = e < 1 ? 1 : e;
  }
}

// ---------------- host ----------------
extern "C" void kernel_launch(void* const* d_in, const int* in_sizes, int n_in,
                              void* d_out, int out_size, void* d_ws, size_t ws_size,
                              hipStream_t stream) {
  (void)in_sizes; (void)n_in; (void)out_size; (void)ws_size;
  const float* neural     = (const float*)d_in[0];
  const int*   lengths    = (const int*)d_in[1];
  const int*   day_idx    = (const int*)d_in[2];
  const float* day_W      = (const float*)d_in[3];
  const float* day_b      = (const float*)d_in[4];
  const float* pe_ln1_w   = (const float*)d_in[5];
  const float* pe_ln1_b   = (const float*)d_in[6];
  const float* pe_W       = (const float*)d_in[7];
  const float* pe_b       = (const float*)d_in[8];
  const float* pe_ln2_w   = (const float*)d_in[9];
  const float* pe_ln2_b   = (const float*)d_in[10];
  const float* ln_attn_w  = (const float*)d_in[11];
  const float* ln_attn_b  = (const float*)d_in[12];
  const float* qkv_W      = (const float*)d_in[13];
  const float* qkv_b      = (const float*)d_in[14];
  const float* attn_out_W = (const float*)d_in[15];
  const float* attn_out_b = (const float*)d_in[16];
  const float* ff_ln_w    = (const float*)d_in[17];
  const float* ff_ln_b    = (const float*)d_in[18];
  const float* fc1_W      = (const float*)d_in[19];
  const float* fc1_b      = (const float*)d_in[20];
  const float* fc2_W      = (const float*)d_in[21];
  const float* fc2_b      = (const float*)d_in[22];
  const float* final_ln_w = (const float*)d_in[23];
  const float* final_ln_b = (const float*)d_in[24];
  const float* ih_W       = (const float*)d_in[25];
  const float* ih_b       = (const float*)d_in[26];
  const float* fb_W       = (const float*)d_in[27];
  const float* fb_b       = (const float*)d_in[28];
  const float* fh_W       = (const float*)d_in[29];
  const float* fh_b       = (const float*)d_in[30];
  const float* dh_W       = (const float*)d_in[31];
  const float* dh_b       = (const float*)d_in[32];

  float* out = (float*)d_out;
  char* p = (char*)d_ws;

  float*    buf_x    = (float*)p;          p += 67117056;   // 8*8193*256 fp32
  ushort_t* buf_pein = (ushort_t*)p;                        // pe-LN out, later qkv
  ushort_t* buf_qkv  = (ushort_t*)p;       p += 33546240;   // 4680*3584 bf16
  float*    buf_h    = (float*)p;          p += 19169280;   // 4680*1024 fp32
  ushort_t* buf_abf  = (ushort_t*)p;       p += 9584640;    // 4680*1024 bf16
  ushort_t* buf_ao   = (ushort_t*)p;       p += 9584640;
  char*     ffp      = p;                  p += 38338560;   // 4680*4096 bf16
  ushort_t* wbuf     = (ushort_t*)p;       p += 25380864;   // 12,690,432 bf16
  int*      eff      = (int*)p;            p += 32;

  ushort_t* buf_ff   = (ushort_t*)ffp;
  float*    buf_dip  = (float*)ffp;                         // overlays (dead ff)
  float*    buf_blank= (float*)(ffp + 29952000);
  ushort_t* buf_probs= (ushort_t*)(ffp + 30719520);
  float*    buf_peout= buf_x;                               // overlays buf_x (dead)
  ushort_t* buf_vt   = (ushort_t*)buf_x;                    // V^T, overlays buf_x (dead after pe)
  ushort_t* dayWt    = buf_ao;                              // day W^T bf16, dead before layer loop

  // wbuf element offsets
  ushort_t* qkvT = wbuf;                 // 3,145,728
  ushort_t* aoT  = wbuf + 3145728;       // 1,048,576
  ushort_t* fc1T = wbuf + 4194304;       // 4,194,304
  ushort_t* fc2T = wbuf + 8388608;       // 4,194,304
  ushort_t* ihT  = wbuf + 12582912;      // 41,984
  ushort_t* fbT  = wbuf + 12624896;      // 65,536
  ushort_t* peT  = wbuf;                 // pre-loop only (3,670,016)
  ushort_t* dhT  = wbuf;                 // post-loop (1,638,400)
  ushort_t* fhT  = wbuf + 1638400;       // post-loop (41,984)

  auto convt = [&](const float* in, ushort_t* o, int R, int C, int Rp) {
    dim3 g((Rp + 31) / 32, (C + 31) / 32);
    convt_kernel<<<g, dim3(32, 8), 0, stream>>>(in, o, R, C, Rp);
  };
  auto gemm = [&](const ushort_t* A, const ushort_t* Bt, const float* bias,
                  float* Cf, ushort_t* Cb, int M_, int N_, int K_, int epi) {
    dim3 g((M_ + BM - 1) / BM, (N_ + BN - 1) / BN);
    gemm_bf16<<<g, 256, 0, stream>>>(A, Bt, bias, Cf, Cb, M_, N_, K_, epi, eff);
  };

  eff_kernel<<<1, 64, 0, stream>>>(lengths, eff);
  dayt_kernel<<<dim3(8, 8, Bz), dim3(32, 8), 0, stream>>>(day_W, day_idx, dayWt);
  smooth_kernel<<<dim3((TmD + TCH - 1) / TCH, Bz), 256, 0, stream>>>(neural, buf_x);
  day_mfma<<<dim3((TmD + DBM - 1) / DBM, Bz), 256, 0, stream>>>(buf_x, dayWt, day_b, day_idx, lengths);

  ln_kernel<<<MTOK, 256, 0, stream>>>(buf_x, pe_ln1_w, pe_ln1_b, nullptr, buf_pein,
                                      PEIN, 1e-6f, Ss, (long)TmD * NEU, (long)KL * NEU);
  convt(pe_W, peT, PEIN, Dm, PEIN);
  convt(ih_W, ihT, Dm, BLANK, Dm);
  convt(fb_W, fbT, BLANK, Dm, 64);
  gemm(buf_pein, peT, pe_b, buf_peout, nullptr, MTOK, Dm, PEIN, 0);
  ln_kernel<<<MTOK, 256, 0, stream>>>(buf_peout, pe_ln2_w, pe_ln2_b, buf_h, nullptr,
                                      Dm, 1e-6f, MTOK, 0L, (long)Dm);

  const int nQT = (Ss + 15) / 16;        // 37
  const int fgx = (nQT + 3) / 4;         // 10

  for (int i = 0; i < Ll; i++) {
    convt(qkv_W + (size_t)i * Dm * 3 * Dm, qkvT, Dm, 3 * Dm, Dm);
    convt(attn_out_W + (size_t)i * Dm * Dm, aoT, Dm, Dm, Dm);
    convt(fc1_W + (size_t)i * Dm * FFd, fc1T, Dm, FFd, Dm);
    convt(fc2_W + (size_t)i * FFd * Dm, fc2T, FFd, Dm, FFd);

    ln_kernel<<<MTOK, 256, 0, stream>>>(buf_h, ln_attn_w + (size_t)i * Dm,
                                        ln_attn_b + (size_t)i * Dm, nullptr, buf_abf,
                                        Dm, 1e-5f, MTOK, 0L, (long)Dm);
    gemm(buf_abf, qkvT, qkv_b + (size_t)i * 3 * Dm, nullptr, buf_qkv,
         MTOK, 3 * Dm, Dm, 4);
    vt_kernel<<<dim3(SpV / 32, Hh * 2, Bz), dim3(32, 8), 0, stream>>>(buf_qkv, buf_vt);
    fattn_kernel<<<dim3(fgx, Hh, Bz), 256, 0, stream>>>(buf_qkv, buf_vt, buf_ao, eff);
    gemm(buf_ao, aoT, attn_out_b + (size_t)i * Dm, buf_h, nullptr,
         MTOK, Dm, Dm, 3);
    ln_kernel<<<MTOK, 256, 0, stream>>>(buf_h, ff_ln_w + (size_t)i * Dm,
                                        ff_ln_b + (size_t)i * Dm, nullptr, buf_abf,
                                        Dm, 1e-5f, MTOK, 0L, (long)Dm);
    gemm(buf_abf, fc1T, fc1_b + (size_t)i * FFd, nullptr, buf_ff,
         MTOK, FFd, Dm, 1);
    gemm(buf_ff, fc2T, fc2_b + (size_t)i * Dm, buf_h, nullptr,
         MTOK, Dm, FFd, 2);
    if (i == 3) {
      f2b_kernel<<<1024, 256, 0, stream>>>(buf_h, buf_abf, MTOK * Dm);
      gemm(buf_abf, ihT, ih_b, buf_blank, nullptr, MTOK, BLANK, Dm, 0);
      lsm41_kernel<<<MTOK, 64, 0, stream>>>(buf_blank, out + (size_t)MTOK * BLANK, buf_probs);
      gemm(buf_probs, fbT, fb_b, buf_h, nullptr, MTOK, Dm, 64, 2);
    }
  }

  ln_kernel<<<MTOK, 256, 0, stream>>>(buf_h, final_ln_w, final_ln_b, nullptr, buf_abf,
                                      Dm, 1e-5f, MTOK, 0L, (long)Dm);
  convt(dh_W, dhT, Dm, DIPd * DIPd, Dm);
  convt(fh_W, fhT, Dm, BLANK, Dm);
  gemm(buf_abf, fhT, fh_b, buf_blank, nullptr, MTOK, BLANK, Dm, 0);
  lsm41_kernel<<<MTOK, 64, 0, stream>>>(buf_blank, out, nullptr);
  gemm(buf_abf, dhT, dh_b, buf_dip, nullptr, MTOK, DIPd * DIPd, Dm, 0);
  diphone_kernel<<<MTOK, 64, 0, stream>>>(buf_dip, out + (size_t)2 * MTOK * BLANK);
}

// Round 5
// 4362.657 us; speedup vs baseline: 1.1531x; 1.0936x over previous
//
#include <hip/hip_runtime.h>
#include <math.h>

// ---------------- constants ----------------
#define Bz    8
#define Tt    8192
#define NEU   256
#define Dm    1024
#define Hh    16
#define Ll    8
#define FFd   4096
#define HDd   64
#define KL    14
#define BLANK 41
#define DIPd  40
#define GKS   20
#define TmD   8193              // T+1 after even-kernel conv
#define Ss    585               // Tm // KL
#define PEIN  3584              // KL*NEU
#define MTOK  (Bz * Ss)         // 4680
#define SpV   608               // Ss padded to multiple of 32 (V^T inner dim)
#define TCH   128               // smooth time-chunk per block

#define NEG_INF (-3.4e38f)

typedef __attribute__((ext_vector_type(8))) short short8;
typedef __attribute__((ext_vector_type(4))) float f32x4;
typedef __attribute__((ext_vector_type(4))) unsigned short us4;
typedef unsigned short ushort_t;

__device__ __forceinline__ float bf2f(ushort_t u) {
  union { unsigned int i; float f; } v; v.i = ((unsigned int)u) << 16; return v.f;
}
__device__ __forceinline__ ushort_t f2bf(float f) {
  union { float f; unsigned int i; } v; v.f = f;
  unsigned int x = v.i;
  if ((x & 0x7fffffffu) > 0x7f800000u) return 0x7fc0;
  return (ushort_t)((x + 0x7fffu + ((x >> 16) & 1u)) >> 16);
}

// ---------------- gaussian smoothing along time ----------------
// Register sliding window: one block per (b, TCH-step chunk); thread = channel.
__global__ __launch_bounds__(256) void smooth_kernel(
    const float* __restrict__ neural, float* __restrict__ out) {
  const int b = blockIdx.y, c = threadIdx.x;
  const int t0 = blockIdx.x * TCH;
  float w[GKS];
  float wsum = 0.f;
#pragma unroll
  for (int j = 0; j < GKS; j++) {
    float e = (j - 9.5f) * 0.5f;
    w[j] = expf(-0.5f * e * e);
    wsum += w[j];
  }
  const float inv = 1.f / wsum;
#pragma unroll
  for (int j = 0; j < GKS; j++) w[j] *= inv;

  const float* src = neural + (size_t)b * Tt * NEU + c;
  float* dst = out + ((size_t)b * TmD + t0) * NEU + c;

  float win[GKS];
#pragma unroll
  for (int j = 0; j < GKS; j++) {
    const int tt = t0 - GKS / 2 + j;
    win[j] = (tt >= 0 && tt < Tt) ? src[(size_t)tt * NEU] : 0.f;
  }
  const int nt = min(TCH, TmD - t0);
  for (int t = 0; t < nt; t++) {
    const int tt = t0 + t + GKS / 2;
    const float nv = (tt < Tt) ? src[(size_t)tt * NEU] : 0.f;
    float acc = 0.f;
#pragma unroll
    for (int j = 0; j < GKS; j++) acc += win[j] * w[j];
    dst[(size_t)t * NEU] = acc;
#pragma unroll
    for (int j = 0; j < GKS - 1; j++) win[j] = win[j + 1];
    win[GKS - 1] = nv;
  }
}

// ---------------- day W pre-transpose: out[b][c][k] = bf16(W[di[b]][k][c]) ----------------
__global__ __launch_bounds__(256) void dayt_kernel(
    const float* __restrict__ dayW, const int* __restrict__ day_idx,
    ushort_t* __restrict__ out) {
  __shared__ float t[32][33];
  const int b = blockIdx.z;
  const int k0 = blockIdx.x * 32, c0 = blockIdx.y * 32;
  const int tx = threadIdx.x, ty = threadIdx.y;   // 32 x 8
  const float* W = dayW + (size_t)day_idx[b] * NEU * NEU;
#pragma unroll
  for (int i = 0; i < 4; i++)
    t[ty + i * 8][tx] = W[(size_t)(k0 + ty + i * 8) * NEU + c0 + tx];
  __syncthreads();
  ushort_t* o = out + (size_t)b * NEU * NEU;
#pragma unroll
  for (int i = 0; i < 4; i++)
    o[(size_t)(c0 + ty + i * 8) * NEU + k0 + tx] = f2bf(t[tx][ty + i * 8]);
}

// ---------------- day linear via MFMA (split hi/lo bf16, ~fp32-exact) ----------------
#define DBM 64
#define DBK 32
__global__ __launch_bounds__(256) void day_mfma(
    float* __restrict__ x, const ushort_t* __restrict__ Wt,
    const float* __restrict__ dayB, const int* __restrict__ day_idx,
    const int* __restrict__ lengths) {
  const int b = blockIdx.y;
  const int bm = blockIdx.x * DBM;
  const int tid = threadIdx.x;
  const int wave = tid >> 6, lane = tid & 63;
  const int lm = lane & 15, quad = lane >> 4;
  const int di = day_idx[b];
  const int len = lengths[b];
  __shared__ ushort_t Ahi[DBM][40], Alo[DBM][40], Bs[256][40];
  f32x4 acc[4][4] = {};
  const float* xb = x + (size_t)b * TmD * NEU;
  const ushort_t* wt = Wt + (size_t)b * NEU * NEU;

  for (int k0 = 0; k0 < NEU; k0 += DBK) {
    __syncthreads();
#pragma unroll
    for (int i = 0; i < 2; i++) {
      const int f = tid + i * 256;          // 0..511
      const int row = f >> 3, kq = f & 7;
      const int gr = min(bm + row, TmD - 1);
      const float4 v = *(const float4*)&xb[(size_t)gr * NEU + k0 + kq * 4];
      const float vv[4] = {v.x, v.y, v.z, v.w};
      us4 hv, lv;
#pragma unroll
      for (int j = 0; j < 4; j++) {
        union { float f; unsigned int u; } uu; uu.f = vv[j];
        const ushort_t h = (ushort_t)(uu.u >> 16);   // truncate-to-bf16
        hv[j] = h;
        lv[j] = f2bf(vv[j] - bf2f(h));
      }
      *(us4*)&Ahi[row][kq * 4] = hv;
      *(us4*)&Alo[row][kq * 4] = lv;
    }
#pragma unroll
    for (int i = 0; i < 4; i++) {
      const int u = tid + i * 256;          // 0..1023
      const int c = u >> 2, kq8 = u & 3;
      const short8 wv = *(const short8*)&wt[(size_t)c * NEU + k0 + kq8 * 8];
      *(short8*)&Bs[c][kq8 * 8] = wv;
    }
    __syncthreads();
    short8 ah[4], al[4], bfr[4];
#pragma unroll
    for (int mt = 0; mt < 4; mt++) {
      ah[mt] = *(const short8*)&Ahi[mt * 16 + lm][quad * 8];
      al[mt] = *(const short8*)&Alo[mt * 16 + lm][quad * 8];
    }
#pragma unroll
    for (int nt = 0; nt < 4; nt++)
      bfr[nt] = *(const short8*)&Bs[wave * 64 + nt * 16 + lm][quad * 8];
#pragma unroll
    for (int mt = 0; mt < 4; mt++)
#pragma unroll
      for (int nt = 0; nt < 4; nt++) {
        acc[mt][nt] = __builtin_amdgcn_mfma_f32_16x16x32_bf16(
            ah[mt], bfr[nt], acc[mt][nt], 0, 0, 0);
        acc[mt][nt] = __builtin_amdgcn_mfma_f32_16x16x32_bf16(
            al[mt], bfr[nt], acc[mt][nt], 0, 0, 0);
      }
  }

#pragma unroll
  for (int mt = 0; mt < 4; mt++)
#pragma unroll
    for (int r = 0; r < 4; r++) {
      const int gm = bm + mt * 16 + quad * 4 + r;
      if (gm >= TmD) continue;
#pragma unroll
      for (int nt = 0; nt < 4; nt++) {
        const int gn = wave * 64 + nt * 16 + lm;
        float v = acc[mt][nt][r] + dayB[(size_t)di * NEU + gn];
        v = v / (1.f + fabsf(v));
        x[((size_t)b * TmD + gm) * NEU + gn] = (gm < len) ? v : 0.f;
      }
    }
}

// ---------------- generic layernorm (fp32 in, fp32 or bf16 out) ----------------
__global__ __launch_bounds__(256) void ln_kernel(
    const float* __restrict__ in, const float* __restrict__ w,
    const float* __restrict__ bias, float* __restrict__ dstf,
    ushort_t* __restrict__ dstb,
    int N, float eps, int inner, long strideA, long strideB) {
  const int row = blockIdx.x;
  const float* src = in + (size_t)(row / inner) * strideA + (size_t)(row % inner) * strideB;
  const int tid = threadIdx.x;
  float s = 0.f, ss = 0.f;
  for (int i = tid; i < N; i += 256) {
    float v = src[i];
    s += v; ss += v * v;
  }
  __shared__ float rs[256], rss[256];
  rs[tid] = s; rss[tid] = ss;
  __syncthreads();
  for (int k = 128; k > 0; k >>= 1) {
    if (tid < k) { rs[tid] += rs[tid + k]; rss[tid] += rss[tid + k]; }
    __syncthreads();
  }
  const float mean = rs[0] / N;
  const float var = rss[0] / N - mean * mean;
  const float rstd = rsqrtf(var + eps);
  for (int i = tid; i < N; i += 256) {
    const float r = (src[i] - mean) * rstd * w[i] + bias[i];
    if (dstf) dstf[(size_t)row * N + i] = r;
    else dstb[(size_t)row * N + i] = f2bf(r);
  }
}

// ---------------- fp32 -> bf16 transpose (+ K zero-pad) ----------------
__global__ __launch_bounds__(256) void convt_kernel(
    const float* __restrict__ in, ushort_t* __restrict__ out,
    int R, int C, int Rp) {
  __shared__ float t[32][33];
  const int r0 = blockIdx.x * 32, c0 = blockIdx.y * 32;
  const int tx = threadIdx.x, ty = threadIdx.y;   // 32 x 8
#pragma unroll
  for (int i = 0; i < 4; i++) {
    const int r = r0 + ty + i * 8, c = c0 + tx;
    t[ty + i * 8][tx] = (r < R && c < C) ? in[(size_t)r * C + c] : 0.f;
  }
  __syncthreads();
#pragma unroll
  for (int i = 0; i < 4; i++) {
    const int c = c0 + ty + i * 8, r = r0 + tx;
    if (c < C && r < Rp) out[(size_t)c * Rp + r] = f2bf(t[tx][ty + i * 8]);
  }
}

// ---------------- fp32 -> bf16 elementwise ----------------
__global__ __launch_bounds__(256) void f2b_kernel(
    const float* __restrict__ in, ushort_t* __restrict__ out, int n) {
  for (int i = blockIdx.x * 256 + threadIdx.x; i < n; i += gridDim.x * 256)
    out[i] = f2bf(in[i]);
}

// ---------------- bf16 MFMA GEMM: C = epi(A[M,K] @ Bt[N,K]^T + bias) ----------------
// epi 0: store fp32  1: gelu->bf16  2: fp32 C += r  3: masked fp32 C += r  4: store bf16
// Tile is templated: <128,128> = 2x2 waves x 4x4 frags (verified config);
// <64,64> = 2x2 waves x 2x2 frags -> 4x the block count for narrow-N GEMMs
// (fc2/ao/pe at N=1024 had only 296 blocks / 256 CUs = occupancy-bound).
#define BKh 32
template <int TM, int TN>
__global__ __launch_bounds__(256) void gemm_bf16(
    const ushort_t* __restrict__ A, const ushort_t* __restrict__ Bt,
    const float* __restrict__ bias, float* __restrict__ Cf,
    ushort_t* __restrict__ Cb, int M, int N, int K, int epi,
    const int* __restrict__ eff) {
  constexpr int MT = TM / 32;           // frags per wave in M (4 or 2)
  constexpr int NT = TN / 32;           // frags per wave in N (4 or 2)
  constexpr int ACH = TM / 16;          // A stage chunks
  constexpr int TCHK = (TM + TN) / 16;  // total stage chunks (<=16)
  __shared__ short As[TM * BKh];
  __shared__ short Bs[TN * BKh];
  const int tid = threadIdx.x;
  const int wave = tid >> 6, lane = tid & 63;
  const int lm = lane & 15, quad = lane >> 4;
  const int bm = blockIdx.x * TM, bn = blockIdx.y * TN;
  const int wm = (wave >> 1) * (MT * 16), wn = (wave & 1) * (NT * 16);

  f32x4 acc[MT][NT] = {};

  const int ldrow = lane >> 2;          // 0..15
  const int ldk = (lane & 3) * 8;       // k offset in halfs

  for (int k0 = 0; k0 < K; k0 += BKh) {
#pragma unroll
    for (int r = 0; r < 4; r++) {
      const int cid = wave * 4 + r;     // 0..15, wave-uniform
      if (cid < ACH) {
        int row = bm + cid * 16 + ldrow;
        row = min(row, M - 1);
        const ushort_t* gp = A + (size_t)row * K + k0 + ldk;
        __builtin_amdgcn_global_load_lds(
            (const __attribute__((address_space(1))) unsigned int*)gp,
            (__attribute__((address_space(3))) unsigned int*)((char*)As + cid * 1024),
            16, 0, 0);
      } else if (cid < TCHK) {
        int row = bn + (cid - ACH) * 16 + ldrow;
        row = min(row, N - 1);
        const ushort_t* gp = Bt + (size_t)row * K + k0 + ldk;
        __builtin_amdgcn_global_load_lds(
            (const __attribute__((address_space(1))) unsigned int*)gp,
            (__attribute__((address_space(3))) unsigned int*)((char*)Bs + (cid - ACH) * 1024),
            16, 0, 0);
      }
    }
    __syncthreads();
    short8 af[MT], bf[NT];
#pragma unroll
    for (int mt = 0; mt < MT; mt++)
      af[mt] = *(const short8*)&As[(wm + mt * 16 + lm) * BKh + quad * 8];
#pragma unroll
    for (int nt = 0; nt < NT; nt++)
      bf[nt] = *(const short8*)&Bs[(wn + nt * 16 + lm) * BKh + quad * 8];
#pragma unroll
    for (int mt = 0; mt < MT; mt++)
#pragma unroll
      for (int nt = 0; nt < NT; nt++)
        acc[mt][nt] = __builtin_amdgcn_mfma_f32_16x16x32_bf16(
            af[mt], bf[nt], acc[mt][nt], 0, 0, 0);
    __syncthreads();
  }

#pragma unroll
  for (int mt = 0; mt < MT; mt++) {
#pragma unroll
    for (int r = 0; r < 4; r++) {
      const int gm = bm + wm + mt * 16 + quad * 4 + r;
      if (gm >= M) continue;
      bool masked = false;
      if (epi == 3) masked = ((gm % Ss) >= eff[gm / Ss]);
#pragma unroll
      for (int nt = 0; nt < NT; nt++) {
        const int gn = bn + wn + nt * 16 + lm;
        if (gn >= N) continue;
        const float v = acc[mt][nt][r] + bias[gn];
        const size_t o = (size_t)gm * N + gn;
        if (epi == 0) Cf[o] = v;
        else if (epi == 1) Cb[o] = f2bf(0.5f * v * (1.f + erff(v * 0.70710678118654752f)));
        else if (epi == 2) Cf[o] += v;
        else if (epi == 3) { if (!masked) Cf[o] += v; }
        else Cb[o] = f2bf(v);
      }
    }
  }
}

// ---------------- V transpose: qkv V-slab -> Vt[b][h][d][SpV] bf16 ----------------
__global__ __launch_bounds__(256) void vt_kernel(
    const ushort_t* __restrict__ qkv, ushort_t* __restrict__ vt) {
  __shared__ ushort_t t[32][33];
  const int s0 = blockIdx.x * 32;
  const int h = blockIdx.y >> 1, d0 = (blockIdx.y & 1) * 32;
  const int b = blockIdx.z;
  const int tx = threadIdx.x, ty = threadIdx.y;
#pragma unroll
  for (int i = 0; i < 4; i++) {
    const int s = s0 + ty + i * 8;
    t[ty + i * 8][tx] = (s < Ss)
        ? qkv[((size_t)(b * Ss + s) * 3 + 2) * Dm + h * HDd + d0 + tx]
        : (ushort_t)0;
  }
  __syncthreads();
#pragma unroll
  for (int i = 0; i < 4; i++) {
    const int d = d0 + ty + i * 8;
    vt[((size_t)(b * Hh + h) * HDd + d) * SpV + s0 + tx] = t[tx][ty + i * 8];
  }
}

// ---------------- MFMA flash attention ----------------
__global__ __launch_bounds__(256) void fattn_kernel(
    const ushort_t* __restrict__ qkv, const ushort_t* __restrict__ vt,
    ushort_t* __restrict__ out, const int* __restrict__ eff) {
  const int wave = threadIdx.x >> 6, lane = threadIdx.x & 63;
  const int lm = lane & 15, quad = lane >> 4;
  const int nQT = (Ss + 15) / 16;                      // 37
  const int qt = ((int)gridDim.x - 1 - (int)blockIdx.x) * 4 + wave;
  if (qt >= nQT) return;
  const int h = blockIdx.y, b = blockIdx.z;
  const int e = eff[b];
  __shared__ ushort_t pl[4][16][40];                   // per-wave P scratch (padded)
  const int q0 = qt * 16;

  const int qrow = min(q0 + lm, Ss - 1);
  const short8* qp = (const short8*)(qkv + (size_t)(b * Ss + qrow) * 3 * Dm + h * HDd + quad * 8);
  const short8 aq0 = qp[0], aq1 = qp[4];

  f32x4 acc[4] = {};
  float mrow[4], lrow[4];
#pragma unroll
  for (int r = 0; r < 4; r++) { mrow[r] = NEG_INF; lrow[r] = 0.f; }

  const int kmax = min(q0 + 15, e - 1);
  const int ntiles = (kmax >> 5) + 1;

  for (int kt = 0; kt < ntiles; kt++) {
    const int k0 = kt * 32;
    f32x4 s0 = {}, s1 = {};
    {
      const int c = min(k0 + lm, Ss - 1);
      const short8* kp = (const short8*)(qkv + ((size_t)(b * Ss + c) * 3 + 1) * Dm + h * HDd + quad * 8);
      s0 = __builtin_amdgcn_mfma_f32_16x16x32_bf16(aq0, kp[0], s0, 0, 0, 0);
      s0 = __builtin_amdgcn_mfma_f32_16x16x32_bf16(aq1, kp[4], s0, 0, 0, 0);
    }
    {
      const int c = min(k0 + 16 + lm, Ss - 1);
      const short8* kp = (const short8*)(qkv + ((size_t)(b * Ss + c) * 3 + 1) * Dm + h * HDd + quad * 8);
      s1 = __builtin_amdgcn_mfma_f32_16x16x32_bf16(aq0, kp[0], s1, 0, 0, 0);
      s1 = __builtin_amdgcn_mfma_f32_16x16x32_bf16(aq1, kp[4], s1, 0, 0, 0);
    }
    float sv0[4], sv1[4], tm[4];
#pragma unroll
    for (int r = 0; r < 4; r++) {
      const int row = q0 + quad * 4 + r;
      const int jm = min(row, e - 1);
      sv0[r] = (k0 + lm <= jm) ? s0[r] * 0.125f : NEG_INF;
      sv1[r] = (k0 + 16 + lm <= jm) ? s1[r] * 0.125f : NEG_INF;
      tm[r] = fmaxf(sv0[r], sv1[r]);
    }
#pragma unroll
    for (int off = 8; off; off >>= 1)
#pragma unroll
      for (int r = 0; r < 4; r++) tm[r] = fmaxf(tm[r], __shfl_xor(tm[r], off));
    float ps[4];
#pragma unroll
    for (int r = 0; r < 4; r++) {
      const float nm = fmaxf(mrow[r], tm[r]);
      const float sc = expf(mrow[r] - nm);
      mrow[r] = nm;
      const float p0 = expf(sv0[r] - nm);
      const float p1 = expf(sv1[r] - nm);
      sv0[r] = p0; sv1[r] = p1;
      ps[r] = p0 + p1;
      lrow[r] *= sc;
#pragma unroll
      for (int nt = 0; nt < 4; nt++) acc[nt][r] *= sc;
    }
#pragma unroll
    for (int off = 8; off; off >>= 1)
#pragma unroll
      for (int r = 0; r < 4; r++) ps[r] += __shfl_xor(ps[r], off);
#pragma unroll
    for (int r = 0; r < 4; r++) {
      lrow[r] += ps[r];
      pl[wave][quad * 4 + r][lm] = f2bf(sv0[r]);
      pl[wave][quad * 4 + r][16 + lm] = f2bf(sv1[r]);
    }
    const short8 pf = *(const short8*)&pl[wave][lm][quad * 8];
    const ushort_t* vtb = vt + (size_t)(b * Hh + h) * HDd * SpV + k0 + quad * 8;
#pragma unroll
    for (int nt = 0; nt < 4; nt++) {
      const short8 vf = *(const short8*)(vtb + (size_t)(nt * 16 + lm) * SpV);
      acc[nt] = __builtin_amdgcn_mfma_f32_16x16x32_bf16(pf, vf, acc[nt], 0, 0, 0);
    }
  }

#pragma unroll
  for (int r = 0; r < 4; r++) {
    const int row = q0 + quad * 4 + r;
    if (row >= Ss) continue;
    const float inv = 1.f / lrow[r];
#pragma unroll
    for (int nt = 0; nt < 4; nt++)
      out[(size_t)(b * Ss + row) * Dm + h * HDd + nt * 16 + lm] = f2bf(acc[nt][r] * inv);
  }
}

// ---------------- log_softmax over 41, optional bf16 probs (padded to 64) ----------------
__global__ __launch_bounds__(64) void lsm41_kernel(
    const float* __restrict__ in, float* __restrict__ lp,
    ushort_t* __restrict__ probs) {
  const int row = blockIdx.x, t = threadIdx.x;
  const float z = (t < BLANK) ? in[(size_t)row * BLANK + t] : NEG_INF;
  float m = z;
#pragma unroll
  for (int off = 32; off; off >>= 1) m = fmaxf(m, __shfl_xor(m, off));
  float s = (t < BLANK) ? expf(z - m) : 0.f;
#pragma unroll
  for (int off = 32; off; off >>= 1) s += __shfl_xor(s, off);
  const float l = z - m - logf(s);
  if (t < BLANK) lp[(size_t)row * BLANK + t] = l;
  if (probs) probs[(size_t)row * 64 + t] = (t < BLANK) ? f2bf(expf(l)) : 0;
}

// ---------------- diphone marginalization ----------------
__global__ __launch_bounds__(64) void diphone_kernel(
    const float* __restrict__ in, float* __restrict__ out) {
  __shared__ float z[DIPd * DIPd];
  __shared__ float u[DIPd];
  const int row = blockIdx.x, t = threadIdx.x;
  for (int i = t; i < DIPd * DIPd; i += 64) z[i] = in[(size_t)row * (DIPd * DIPd) + i];
  __syncthreads();
  if (t < DIPd) {
    float m1 = NEG_INF;
    for (int j = 0; j < DIPd; j++) m1 = fmaxf(m1, z[t * DIPd + j]);
    float s1 = 0.f;
    for (int j = 0; j < DIPd; j++) s1 += expf(z[t * DIPd + j] - m1);
    const float lr = m1 + logf(s1);
    float m2 = NEG_INF;
    for (int j = 0; j < DIPd; j++) m2 = fmaxf(m2, z[j * DIPd + t]);
    float s2 = 0.f;
    for (int j = 0; j < DIPd; j++) s2 += expf(z[j * DIPd + t] - m2);
    const float lc = m2 + logf(s2);
    const float mx = fmaxf(lr, lc), mn = fminf(lr, lc);
    u[t] = mx + log1pf(expf(mn - mx));
  }
  __syncthreads();
  const float v = (t < DIPd) ? u[t] : NEG_INF;
  float m = v;
#pragma unroll
  for (int off = 32; off; off >>= 1) m = fmaxf(m, __shfl_xor(m, off));
  float s = (t < DIPd) ? expf(v - m) : 0.f;
#pragma unroll
  for (int off = 32; off; off >>= 1) s += __shfl_xor(s, off);
  const float lse = m + logf(s);
  if (t < DIPd) out[(size_t)row * DIPd + t] = v - lse;
}

__global__ void eff_kernel(const int* __restrict__ lengths, int* __restrict__ eff) {
  const int t = threadIdx.x;
  if (t < Bz) {
    int e = lengths[t] / KL;
    eff[t] = e < 1 ? 1 : e;
  }
}

// ---------------- host ----------------
extern "C" void kernel_launch(void* const* d_in, const int* in_sizes, int n_in,
                              void* d_out, int out_size, void* d_ws, size_t ws_size,
                              hipStream_t stream) {
  (void)in_sizes; (void)n_in; (void)out_size; (void)ws_size;
  const float* neural     = (const float*)d_in[0];
  const int*   lengths    = (const int*)d_in[1];
  const int*   day_idx    = (const int*)d_in[2];
  const float* day_W      = (const float*)d_in[3];
  const float* day_b      = (const float*)d_in[4];
  const float* pe_ln1_w   = (const float*)d_in[5];
  const float* pe_ln1_b   = (const float*)d_in[6];
  const float* pe_W       = (const float*)d_in[7];
  const float* pe_b       = (const float*)d_in[8];
  const float* pe_ln2_w   = (const float*)d_in[9];
  const float* pe_ln2_b   = (const float*)d_in[10];
  const float* ln_attn_w  = (const float*)d_in[11];
  const float* ln_attn_b  = (const float*)d_in[12];
  const float* qkv_W      = (const float*)d_in[13];
  const float* qkv_b      = (const float*)d_in[14];
  const float* attn_out_W = (const float*)d_in[15];
  const float* attn_out_b = (const float*)d_in[16];
  const float* ff_ln_w    = (const float*)d_in[17];
  const float* ff_ln_b    = (const float*)d_in[18];
  const float* fc1_W      = (const float*)d_in[19];
  const float* fc1_b      = (const float*)d_in[20];
  const float* fc2_W      = (const float*)d_in[21];
  const float* fc2_b      = (const float*)d_in[22];
  const float* final_ln_w = (const float*)d_in[23];
  const float* final_ln_b = (const float*)d_in[24];
  const float* ih_W       = (const float*)d_in[25];
  const float* ih_b       = (const float*)d_in[26];
  const float* fb_W       = (const float*)d_in[27];
  const float* fb_b       = (const float*)d_in[28];
  const float* fh_W       = (const float*)d_in[29];
  const float* fh_b       = (const float*)d_in[30];
  const float* dh_W       = (const float*)d_in[31];
  const float* dh_b       = (const float*)d_in[32];

  float* out = (float*)d_out;
  char* p = (char*)d_ws;

  float*    buf_x    = (float*)p;          p += 67117056;   // 8*8193*256 fp32
  ushort_t* buf_pein = (ushort_t*)p;                        // pe-LN out, later qkv
  ushort_t* buf_qkv  = (ushort_t*)p;       p += 33546240;   // 4680*3584 bf16
  float*    buf_h    = (float*)p;          p += 19169280;   // 4680*1024 fp32
  ushort_t* buf_abf  = (ushort_t*)p;       p += 9584640;    // 4680*1024 bf16
  ushort_t* buf_ao   = (ushort_t*)p;       p += 9584640;
  char*     ffp      = p;                  p += 38338560;   // 4680*4096 bf16
  ushort_t* wbuf     = (ushort_t*)p;       p += 25380864;   // 12,690,432 bf16
  int*      eff      = (int*)p;            p += 32;

  ushort_t* buf_ff   = (ushort_t*)ffp;
  float*    buf_dip  = (float*)ffp;                         // overlays (dead ff)
  float*    buf_blank= (float*)(ffp + 29952000);
  ushort_t* buf_probs= (ushort_t*)(ffp + 30719520);
  float*    buf_peout= buf_x;                               // overlays buf_x (dead)
  ushort_t* buf_vt   = (ushort_t*)buf_x;                    // V^T, overlays buf_x (dead after pe)
  ushort_t* dayWt    = buf_ao;                              // day W^T bf16, dead before layer loop

  // wbuf element offsets
  ushort_t* qkvT = wbuf;                 // 3,145,728
  ushort_t* aoT  = wbuf + 3145728;       // 1,048,576
  ushort_t* fc1T = wbuf + 4194304;       // 4,194,304
  ushort_t* fc2T = wbuf + 8388608;       // 4,194,304
  ushort_t* ihT  = wbuf + 12582912;      // 41,984
  ushort_t* fbT  = wbuf + 12624896;      // 65,536
  ushort_t* peT  = wbuf;                 // pre-loop only (3,670,016)
  ushort_t* dhT  = wbuf;                 // post-loop (1,638,400)
  ushort_t* fhT  = wbuf + 1638400;       // post-loop (41,984)

  auto convt = [&](const float* in, ushort_t* o, int R, int C, int Rp) {
    dim3 g((Rp + 31) / 32, (C + 31) / 32);
    convt_kernel<<<g, dim3(32, 8), 0, stream>>>(in, o, R, C, Rp);
  };
  // Tile choice: 128x128 when the grid is wide enough to fill 256 CUs
  // (>=768 blocks), else 64x64 (4x the blocks) for latency hiding.
  auto gemm = [&](const ushort_t* A, const ushort_t* Bt, const float* bias,
                  float* Cf, ushort_t* Cb, int M_, int N_, int K_, int epi) {
    const long blocks128 = (long)((M_ + 127) / 128) * ((N_ + 127) / 128);
    if (blocks128 >= 768) {
      dim3 g((M_ + 127) / 128, (N_ + 127) / 128);
      gemm_bf16<128, 128><<<g, 256, 0, stream>>>(A, Bt, bias, Cf, Cb, M_, N_, K_, epi, eff);
    } else {
      dim3 g((M_ + 63) / 64, (N_ + 63) / 64);
      gemm_bf16<64, 64><<<g, 256, 0, stream>>>(A, Bt, bias, Cf, Cb, M_, N_, K_, epi, eff);
    }
  };

  eff_kernel<<<1, 64, 0, stream>>>(lengths, eff);
  dayt_kernel<<<dim3(8, 8, Bz), dim3(32, 8), 0, stream>>>(day_W, day_idx, dayWt);
  smooth_kernel<<<dim3((TmD + TCH - 1) / TCH, Bz), 256, 0, stream>>>(neural, buf_x);
  day_mfma<<<dim3((TmD + DBM - 1) / DBM, Bz), 256, 0, stream>>>(buf_x, dayWt, day_b, day_idx, lengths);

  ln_kernel<<<MTOK, 256, 0, stream>>>(buf_x, pe_ln1_w, pe_ln1_b, nullptr, buf_pein,
                                      PEIN, 1e-6f, Ss, (long)TmD * NEU, (long)KL * NEU);
  convt(pe_W, peT, PEIN, Dm, PEIN);
  convt(ih_W, ihT, Dm, BLANK, Dm);
  convt(fb_W, fbT, BLANK, Dm, 64);
  gemm(buf_pein, peT, pe_b, buf_peout, nullptr, MTOK, Dm, PEIN, 0);
  ln_kernel<<<MTOK, 256, 0, stream>>>(buf_peout, pe_ln2_w, pe_ln2_b, buf_h, nullptr,
                                      Dm, 1e-6f, MTOK, 0L, (long)Dm);

  const int nQT = (Ss + 15) / 16;        // 37
  const int fgx = (nQT + 3) / 4;         // 10

  for (int i = 0; i < Ll; i++) {
    convt(qkv_W + (size_t)i * Dm * 3 * Dm, qkvT, Dm, 3 * Dm, Dm);
    convt(attn_out_W + (size_t)i * Dm * Dm, aoT, Dm, Dm, Dm);
    convt(fc1_W + (size_t)i * Dm * FFd, fc1T, Dm, FFd, Dm);
    convt(fc2_W + (size_t)i * FFd * Dm, fc2T, FFd, Dm, FFd);

    ln_kernel<<<MTOK, 256, 0, stream>>>(buf_h, ln_attn_w + (size_t)i * Dm,
                                        ln_attn_b + (size_t)i * Dm, nullptr, buf_abf,
                                        Dm, 1e-5f, MTOK, 0L, (long)Dm);
    gemm(buf_abf, qkvT, qkv_b + (size_t)i * 3 * Dm, nullptr, buf_qkv,
         MTOK, 3 * Dm, Dm, 4);
    vt_kernel<<<dim3(SpV / 32, Hh * 2, Bz), dim3(32, 8), 0, stream>>>(buf_qkv, buf_vt);
    fattn_kernel<<<dim3(fgx, Hh, Bz), 256, 0, stream>>>(buf_qkv, buf_vt, buf_ao, eff);
    gemm(buf_ao, aoT, attn_out_b + (size_t)i * Dm, buf_h, nullptr,
         MTOK, Dm, Dm, 3);
    ln_kernel<<<MTOK, 256, 0, stream>>>(buf_h, ff_ln_w + (size_t)i * Dm,
                                        ff_ln_b + (size_t)i * Dm, nullptr, buf_abf,
                                        Dm, 1e-5f, MTOK, 0L, (long)Dm);
    gemm(buf_abf, fc1T, fc1_b + (size_t)i * FFd, nullptr, buf_ff,
         MTOK, FFd, Dm, 1);
    gemm(buf_ff, fc2T, fc2_b + (size_t)i * Dm, buf_h, nullptr,
         MTOK, Dm, FFd, 2);
    if (i == 3) {
      f2b_kernel<<<1024, 256, 0, stream>>>(buf_h, buf_abf, MTOK * Dm);
      gemm(buf_abf, ihT, ih_b, buf_blank, nullptr, MTOK, BLANK, Dm, 0);
      lsm41_kernel<<<MTOK, 64, 0, stream>>>(buf_blank, out + (size_t)MTOK * BLANK, buf_probs);
      gemm(buf_probs, fbT, fb_b, buf_h, nullptr, MTOK, Dm, 64, 2);
    }
  }

  ln_kernel<<<MTOK, 256, 0, stream>>>(buf_h, final_ln_w, final_ln_b, nullptr, buf_abf,
                                      Dm, 1e-5f, MTOK, 0L, (long)Dm);
  convt(dh_W, dhT, Dm, DIPd * DIPd, Dm);
  convt(fh_W, fhT, Dm, BLANK, Dm);
  gemm(buf_abf, fhT, fh_b, buf_blank, nullptr, MTOK, BLANK, Dm, 0);
  lsm41_kernel<<<MTOK, 64, 0, stream>>>(buf_blank, out, nullptr);
  gemm(buf_abf, dhT, dh_b, buf_dip, nullptr, MTOK, DIPd * DIPd, Dm, 0);
  diphone_kernel<<<MTOK, 64, 0, stream>>>(buf_dip, out + (size_t)2 * MTOK * BLANK);
}